// Round 13
// baseline (183.540 us; speedup 1.0000x reference)
//
#include <hip/hip_runtime.h>

typedef __bf16 bf16x8 __attribute__((ext_vector_type(8)));
typedef __bf16 bf16x4 __attribute__((ext_vector_type(4)));
typedef __bf16 bf16x2 __attribute__((ext_vector_type(2)));
typedef float f32x4 __attribute__((ext_vector_type(4)));
typedef float f32x16 __attribute__((ext_vector_type(16)));
typedef int i32x4 __attribute__((ext_vector_type(4)));
typedef unsigned int u32x2 __attribute__((ext_vector_type(2)));

#define EXP2_SCALE 0.045084439f   // (1/32) * log2(e), folded into Q at gemm_qkv

__device__ __forceinline__ void async16(void* lds, const void* g) {
  __builtin_amdgcn_global_load_lds(
      (__attribute__((address_space(1))) unsigned int*)(g),
      (__attribute__((address_space(3))) unsigned int*)(lds), 16, 0, 0);
}

__device__ __forceinline__ unsigned int pack2(float a, float b) {
  bf16x2 t;
  t[0] = (__bf16)a;
  t[1] = (__bf16)b;
  return __builtin_bit_cast(unsigned int, t);
}

// raw v_exp_f32 (2^x): skips ocml's denormal-guard expansion.
__device__ __forceinline__ float fexp2(float x) {
#if __has_builtin(__builtin_amdgcn_exp2f)
  return __builtin_amdgcn_exp2f(x);
#else
  return exp2f(x);
#endif
}

// lane[i] <-> lane[i+32] half-wave exchange: d.hi <-> s.lo.
__device__ __forceinline__ void plswap(unsigned int& d, unsigned int& s) {
#if __has_builtin(__builtin_amdgcn_permlane32_swap)
  u32x2 r = __builtin_amdgcn_permlane32_swap(d, s, false, false);
  d = r[0];
  s = r[1];
#else
  asm("v_permlane32_swap_b32 %0, %1" : "+v"(d), "+v"(s));
#endif
}

// Per-block dtype self-detect on a 2048-u16 window.
__device__ __forceinline__ int detect_block(const unsigned short* win, int* cnt_sh) {
  if (threadIdx.x == 0) *cnt_sh = 0;
  __syncthreads();
  int c = 0;
#pragma unroll
  for (int j = 0; j < 8; j++) {
    const unsigned short u = win[threadIdx.x * 8 + j];
    if (((u >> 7) & 0xFF) >= 0xC0) c++;
  }
  if (c) atomicAdd(cnt_sh, c);
  __syncthreads();
  return (*cnt_sh >= 64) ? 1 : 0;
}

// ---------------- prep: x->bf16 cvt (blocks 0..2047) + Wqkv transpose
// (2048..2815) + Wout transpose (2816..3071). W-path global reads vectorized
// (bf16x8 / 2x f32x4) and transposed stores written as bf16x8 (R10-verified).
__global__ __launch_bounds__(256) void prep(
    const void* __restrict__ x, const void* __restrict__ Wqkv,
    const void* __restrict__ Wout, __bf16* __restrict__ xb,
    __bf16* __restrict__ WqkvT, __bf16* __restrict__ WoutT,
    int* __restrict__ flagp)
{
  __shared__ __bf16 tile[64 * 65];
  __shared__ int cnt;
  const int bx = blockIdx.x;
  const int t = threadIdx.x;

  if (bx < 2048) {
    const long base = (long)bx * 2048;
    const int f = detect_block((const unsigned short*)x + base, &cnt);
    if (bx == 0 && t == 0) *flagp = f;
    const long i = base + t * 8;
    if (f) {
      const f32x4* s4 = (const f32x4*)((const float*)x + i);
      const f32x4 v0 = s4[0], v1 = s4[1];
      bf16x8 o;
#pragma unroll
      for (int j = 0; j < 4; j++) o[j] = (__bf16)v0[j];
#pragma unroll
      for (int j = 0; j < 4; j++) o[4 + j] = (__bf16)v1[j];
      *(bf16x8*)&xb[i] = o;
    } else {
      *(bf16x8*)&xb[i] = *(const bf16x8*)((const __bf16*)x + i);
    }
    return;
  }

  const void* in;  __bf16* out;  int R = 1024, C, tcx, tr;
  if (bx < 2816) {
    const int idx = bx - 2048;
    in = Wqkv; out = WqkvT; C = 3072; tcx = (idx % 48) * 64; tr = (idx / 48) * 64;
  } else {
    const int idx = bx - 2816;
    in = Wout; out = WoutT; C = 1024; tcx = (idx % 16) * 64; tr = (idx / 16) * 64;
  }
  const int f = detect_block((const unsigned short*)in + (long)tr * C + tcx, &cnt);
#pragma unroll
  for (int j = 0; j < 2; j++) {
    const int i8 = t * 2 + j;              // 0..511
    const int r = i8 >> 3, c8 = (i8 & 7) * 8;
    const long g = (long)(tr + r) * C + tcx + c8;
    if (f) {
      const f32x4* s4 = (const f32x4*)((const float*)in + g);
      const f32x4 v0 = s4[0], v1 = s4[1];
#pragma unroll
      for (int e = 0; e < 4; e++) tile[r * 65 + c8 + e] = (__bf16)v0[e];
#pragma unroll
      for (int e = 0; e < 4; e++) tile[r * 65 + c8 + 4 + e] = (__bf16)v1[e];
    } else {
      const bf16x8 v = *(const bf16x8*)((const __bf16*)in + g);
#pragma unroll
      for (int e = 0; e < 8; e++) tile[r * 65 + c8 + e] = v[e];
    }
  }
  __syncthreads();
#pragma unroll
  for (int j = 0; j < 2; j++) {
    const int i8 = t * 2 + j;
    const int ro = i8 >> 3, co8 = (i8 & 7) * 8;
    bf16x8 v;
#pragma unroll
    for (int e = 0; e < 8; e++) v[e] = tile[(co8 + e) * 65 + ro];
    *(bf16x8*)&out[(long)(tcx + ro) * R + tr + co8] = v;
  }
}

// ---------------- qkv GEMM: [4096,1024] x [1024,3072]^T, prefetch-pipelined.
// Epilogue writes FRAGMENT-NATIVE global layouts for attn:
//   Q  -> qbuf[row][hd]      (pre-scaled by EXP2_SCALE, stride 1024)
//   K  -> K'[bh][kt][g=d>>3][key&63][e=d&7]   (one b128 per attn A-frag)
//   V  -> V'[bh][kt][g=key>>3&7][d][e=key&7]  (one b128 per attn B-frag)
// K' epilogue LDS-repacked (R9). XCD-bijective swizzle (768 = 8*96).
__global__ __launch_bounds__(256, 3) void gemm_qkv(
    const __bf16* __restrict__ A, const __bf16* __restrict__ Bt,
    __bf16* __restrict__ Qb, __bf16* __restrict__ Kc, __bf16* __restrict__ Vc)
{
  __shared__ __bf16 smem[17408];
  const int t = threadIdx.x;
  const int l = t & 63;
  const int w = t >> 6;
  const int wr = w >> 1, wc = w & 1;
  const int lid = blockIdx.y * 32 + blockIdx.x;
  const int s = (lid & 7) * 96 + (lid >> 3);
  const long m0 = (long)(s & 31) * 128;
  const long n0 = (long)(s >> 5) * 128;
  const int K = 1024;

  const int srow = w * 16 + (l >> 2);
  const int skof = (l & 3) * 8;
  const __bf16* gA = A + (m0 + srow) * (long)K + skof;
  const __bf16* gB = Bt + (n0 + srow) * (long)K + skof;
  const int Ao[2] = {0, 8192}, Bo[2] = {4096, 12288};
  const int lof = w * 512 + l * 8;

  async16(smem + Ao[0] + lof,        gA);
  async16(smem + Ao[0] + 2048 + lof, gA + 64 * (long)K);
  async16(smem + Bo[0] + lof,        gB);
  async16(smem + Bo[0] + 2048 + lof, gB + 64 * (long)K);
  gA += 32; gB += 32;
  __syncthreads();

  f32x4 acc[4][4] = {};

  for (int it = 0; it < 32; it++) {
    if (it < 31) {
      const int nb = (it + 1) & 1;
      async16(smem + Ao[nb] + lof,        gA);
      async16(smem + Ao[nb] + 2048 + lof, gA + 64 * (long)K);
      async16(smem + Bo[nb] + lof,        gB);
      async16(smem + Bo[nb] + 2048 + lof, gB + 64 * (long)K);
      gA += 32; gB += 32;
    }
    const __bf16* As = smem + Ao[it & 1];
    const __bf16* Bs = smem + Bo[it & 1];
    bf16x8 af[4], bfr[4];
#pragma unroll
    for (int mi = 0; mi < 4; mi++)
      af[mi] = *(const bf16x8*)&As[(wr * 64 + mi * 16 + (l & 15)) * 32 + (l >> 4) * 8];
#pragma unroll
    for (int ni = 0; ni < 4; ni++)
      bfr[ni] = *(const bf16x8*)&Bs[(wc * 64 + ni * 16 + (l & 15)) * 32 + (l >> 4) * 8];
#pragma unroll
    for (int mi = 0; mi < 4; mi++)
#pragma unroll
      for (int ni = 0; ni < 4; ni++)
        acc[mi][ni] = __builtin_amdgcn_mfma_f32_16x16x32_bf16(af[mi], bfr[ni], acc[mi][ni], 0, 0, 0);
    __syncthreads();
  }

  if (n0 < 1024) {                       // Q (pre-scaled, stride 1024)
#pragma unroll
    for (int mi = 0; mi < 4; mi++)
#pragma unroll
      for (int ni = 0; ni < 4; ni++) {
        const long col = n0 + wc * 64 + ni * 16 + (l & 15);
#pragma unroll
        for (int r = 0; r < 4; r++) {
          const long row = m0 + wr * 64 + mi * 16 + (l >> 4) * 4 + r;
          Qb[row * 1024 + col] = (__bf16)(acc[mi][ni][r] * EXP2_SCALE);
        }
      }
  } else if (n0 < 2048) {                // K -> fragment-native K' (LDS repack)
#pragma unroll
    for (int mi = 0; mi < 4; mi++)
#pragma unroll
      for (int ni = 0; ni < 4; ni++) {
        const int dcol = wc * 64 + ni * 16 + (l & 15);
        const int kl0 = wr * 64 + mi * 16 + (l >> 4) * 4;
#pragma unroll
        for (int r = 0; r < 4; r++)
          smem[(kl0 + r) * 136 + dcol] = (__bf16)acc[mi][ni][r];
      }
    __syncthreads();
    const int b = (int)(m0 >> 11);
    const int nbase = (int)(m0 & 2047);
#pragma unroll
    for (int i = 0; i < 8; i++) {
      const int kl = (t >> 4) + i * 16;          // key_local 0..127
      const int d0 = (t & 15) * 8;               // feature col base 0..120
      const bf16x8 v = *(const bf16x8*)&smem[kl * 136 + d0];
      const int col1 = (int)(n0 - 1024) + d0;    // h*64 + d (d0 multiple of 8)
      const int h = col1 >> 6, d = col1 & 63;
      const int n = nbase + kl;                  // key
      const long addr = ((long)(b * 16 + h) * 32 + (n >> 6)) * 4096 + (d >> 3) * 512 + (n & 63) * 8;
      *(bf16x8*)&Kc[addr] = v;
    }
  } else {                               // V -> fragment-native V'
#pragma unroll
    for (int mi = 0; mi < 4; mi++)
#pragma unroll
      for (int ni = 0; ni < 4; ni++) {
        const int c = wc * 64 + ni * 16 + (l & 15);
        const int r = wr * 64 + mi * 16 + (l >> 4) * 4;
        bf16x4 pk;
#pragma unroll
        for (int k = 0; k < 4; k++) pk[k] = (__bf16)acc[mi][ni][k];
        *(bf16x4*)&smem[c * 136 + r] = pk;
      }
    __syncthreads();
    const int b = (int)(m0 >> 11);
    const int nbase = (int)(m0 & 2047);
#pragma unroll
    for (int i = 0; i < 8; i++) {
      const int c = (t >> 4) + i * 16;
      const int r8 = (t & 15) * 8;
      const bf16x8 v = *(const bf16x8*)&smem[c * 136 + r8];
      const int vcol = (int)(n0 - 2048) + c;         // h*64 + d
      const int h = vcol >> 6, d = vcol & 63;
      const int n = nbase + r8;                      // key base of the 8
      const long addr = ((long)(b * 16 + h) * 32 + (n >> 6)) * 4096 + ((n >> 3) & 7) * 512 + d * 8;
      *(bf16x8*)&Vc[addr] = v;
    }
  }
}

// ---------------- out GEMM: [4096,1024] x [1024,1024]^T + bias, 128x128 tile
// (gemm_qkv's verified main loop). Grid 32x8, XCD-bijective swizzle.
__global__ __launch_bounds__(256, 3) void gemm_out(
    const __bf16* __restrict__ A, const __bf16* __restrict__ Bt,
    const void* __restrict__ bias_raw, void* __restrict__ C,
    const int* __restrict__ flagp)
{
  __shared__ __bf16 smem[16384];
  const int t = threadIdx.x;
  const int l = t & 63;
  const int w = t >> 6;
  const int wr = w >> 1, wc = w & 1;
  const int lid = blockIdx.y * 32 + blockIdx.x;
  const int s = (lid & 7) * 32 + (lid >> 3);
  const long m0 = (long)(s & 31) * 128;
  const long n0 = (long)(s >> 5) * 128;
  const int of = *flagp;
  const int K = 1024;

  const int srow = w * 16 + (l >> 2);
  const int skof = (l & 3) * 8;
  const __bf16* gA = A + (m0 + srow) * (long)K + skof;
  const __bf16* gB = Bt + (n0 + srow) * (long)K + skof;
  const int Ao[2] = {0, 8192}, Bo[2] = {4096, 12288};
  const int lof = w * 512 + l * 8;

  async16(smem + Ao[0] + lof,        gA);
  async16(smem + Ao[0] + 2048 + lof, gA + 64 * (long)K);
  async16(smem + Bo[0] + lof,        gB);
  async16(smem + Bo[0] + 2048 + lof, gB + 64 * (long)K);
  gA += 32; gB += 32;
  __syncthreads();

  f32x4 acc[4][4] = {};

  for (int it = 0; it < 32; it++) {
    if (it < 31) {
      const int nb = (it + 1) & 1;
      async16(smem + Ao[nb] + lof,        gA);
      async16(smem + Ao[nb] + 2048 + lof, gA + 64 * (long)K);
      async16(smem + Bo[nb] + lof,        gB);
      async16(smem + Bo[nb] + 2048 + lof, gB + 64 * (long)K);
      gA += 32; gB += 32;
    }
    const __bf16* As = smem + Ao[it & 1];
    const __bf16* Bs = smem + Bo[it & 1];
    bf16x8 af[4], bfr[4];
#pragma unroll
    for (int mi = 0; mi < 4; mi++)
      af[mi] = *(const bf16x8*)&As[(wr * 64 + mi * 16 + (l & 15)) * 32 + (l >> 4) * 8];
#pragma unroll
    for (int ni = 0; ni < 4; ni++)
      bfr[ni] = *(const bf16x8*)&Bs[(wc * 64 + ni * 16 + (l & 15)) * 32 + (l >> 4) * 8];
#pragma unroll
    for (int mi = 0; mi < 4; mi++)
#pragma unroll
      for (int ni = 0; ni < 4; ni++)
        acc[mi][ni] = __builtin_amdgcn_mfma_f32_16x16x32_bf16(af[mi], bfr[ni], acc[mi][ni], 0, 0, 0);
    __syncthreads();
  }

#pragma unroll
  for (int mi = 0; mi < 4; mi++)
#pragma unroll
    for (int ni = 0; ni < 4; ni++) {
      const long col = n0 + wc * 64 + ni * 16 + (l & 15);
      const float bv = of ? ((const float*)bias_raw)[col]
                          : (float)((const __bf16*)bias_raw)[col];
#pragma unroll
      for (int r = 0; r < 4; r++) {
        const long row = m0 + wr * 64 + mi * 16 + (l >> 4) * 4 + r;
        const float val = acc[mi][ni][r] + bv;
        const long off = row * 1024 + col;
        if (of) ((float*)C)[off] = val;
        else    ((__bf16*)C)[off] = (__bf16)val;
      }
    }
}

// ---------------- flash attention, ZERO-LDS / ZERO-BARRIER, DUAL-Q-STREAM.
// R13: R11 body restored exactly (PV-first: the ready register-only PV
// cluster hides the K-load vmcnt wait at iteration entry — R12's St-first
// regressed 9%). Iterations 0 and 31 PEELED: branch-free 30-iteration core
// (15 unrolled pairs, running pointers), no per-iteration IT>0 / IT<31
// compares.
__global__ __launch_bounds__(256, 2) void attn_kernel(
    const __bf16* __restrict__ Qb, const __bf16* __restrict__ Kc,
    const __bf16* __restrict__ Vc, __bf16* __restrict__ O)
{
  __shared__ float fsm[4 * 1024 + 128];
  const int t = threadIdx.x;
  const int l = t & 63;
  const int w = t >> 6;
  const int wi = w & 1, wj = w >> 1;
  const int hl = l >> 5;
  // XCD swizzle: same bh => same (linear % 8) => same XCD L2.
  const int L = blockIdx.y * 32 + blockIdx.x;
  const int bh = (L & 7) * 4 + ((L >> 3) & 3);
  const int qt = L >> 5;                 // 0..15 (128-row Q tiles)
  const int b = bh >> 4, head = bh & 15;
  const long q_row0 = (long)b * 2048 + qt * 128;

  // Q fragments for both streams (pre-scaled upstream)
  bf16x8 qA0, qA1, qA2, qA3, qB0, qB1, qB2, qB3;
  {
    const __bf16* gQ = Qb + (q_row0 + wi * 32 + (l & 31)) * 1024 + head * 64 + hl * 8;
    qA0 = *(const bf16x8*)(gQ);
    qA1 = *(const bf16x8*)(gQ + 16);
    qA2 = *(const bf16x8*)(gQ + 32);
    qA3 = *(const bf16x8*)(gQ + 48);
    gQ += (long)64 * 1024;
    qB0 = *(const bf16x8*)(gQ);
    qB1 = *(const bf16x8*)(gQ + 16);
    qB2 = *(const bf16x8*)(gQ + 32);
    qB3 = *(const bf16x8*)(gQ + 48);
  }

  const __bf16* kb = Kc + (long)bh * 131072;
  const __bf16* vb = Vc + (long)bh * 131072;
  // K A-frag: (g = kc*2+hl, key = wj*32+(l&31)); frag kc offset = kof0 + kc*1024
  const int kof0 = hl * 512 + (wj * 32 + (l & 31)) * 8;
  // V B-frag: (g = wj*4 + {hl, 2+hl}, d = {l&31, 32+(l&31)})
  const int vof0 = (wj * 4 + hl) * 512 + (l & 31) * 8;   // +256 dhi, +1024 g+2

  f32x16 aAa = {0,0,0,0,0,0,0,0,0,0,0,0,0,0,0,0};  // stream A, d 0..31
  f32x16 aBa = {0,0,0,0,0,0,0,0,0,0,0,0,0,0,0,0};  // stream A, d 32..63
  f32x16 aAb = {0,0,0,0,0,0,0,0,0,0,0,0,0,0,0,0};  // stream B, d 0..31
  f32x16 aBb = {0,0,0,0,0,0,0,0,0,0,0,0,0,0,0,0};  // stream B, d 32..63
  const f32x16 fz = {0,0,0,0,0,0,0,0,0,0,0,0,0,0,0,0};
  float liA = 0.0f, liB = 0.0f;
  bf16x8 paA0 = {}, paA1 = {}, paB0 = {}, paB1 = {};

#define LD8(p) (*(const bf16x8*)(p))
  // tile-0 K into set a
  bf16x8 ka0 = LD8(kb + kof0),        ka1 = LD8(kb + kof0 + 1024);
  bf16x8 ka2 = LD8(kb + kof0 + 2048), ka3 = LD8(kb + kof0 + 3072);
  bf16x8 kn0, kn1, kn2, kn3;
  bf16x8 va0, va1, va2, va3;
  bf16x8 vn0, vn1, vn2, vn3;

#define SM_PACK(ST, PA0, PA1) \
  { \
    unsigned int a0 = pack2(ST[0],  ST[1]),  b0 = pack2(ST[4],  ST[5]); \
    unsigned int c0 = pack2(ST[2],  ST[3]),  d0 = pack2(ST[6],  ST[7]); \
    unsigned int a1 = pack2(ST[8],  ST[9]),  b1 = pack2(ST[12], ST[13]); \
    unsigned int c1 = pack2(ST[10], ST[11]), d1 = pack2(ST[14], ST[15]); \
    plswap(a0, b0); plswap(c0, d0); plswap(a1, b1); plswap(c1, d1); \
    const i32x4 f0_ = {(int)a0, (int)c0, (int)b0, (int)d0}; \
    const i32x4 f1_ = {(int)a1, (int)c1, (int)b1, (int)d1}; \
    PA0 = __builtin_bit_cast(bf16x8, f0_); \
    PA1 = __builtin_bit_cast(bf16x8, f1_); \
  }

#define DO_SOFTMAX_PACK(STA, STB) \
    { float rs0 = 0.0f, rs1 = 0.0f; \
    _Pragma("unroll") \
    for (int r = 0; r < 16; r += 2) { \
      const float p0 = fexp2(STA[r]); \
      const float p1 = fexp2(STA[r + 1]); \
      STA[r] = p0; STA[r + 1] = p1; \
      rs0 += p0; rs1 += p1; \
    } \
    liA += rs0 + rs1; } \
    SM_PACK(STA, paA0, paA1) \
    { float rs0 = 0.0f, rs1 = 0.0f; \
    _Pragma("unroll") \
    for (int r = 0; r < 16; r += 2) { \
      const float p0 = fexp2(STB[r]); \
      const float p1 = fexp2(STB[r + 1]); \
      STB[r] = p0; STB[r + 1] = p1; \
      rs0 += p0; rs1 += p1; \
    } \
    liB += rs0 + rs1; } \
    SM_PACK(STB, paB0, paB1)

#define ST_CLUSTER(KA0,KA1,KA2,KA3) \
    f32x16 stA = __builtin_amdgcn_mfma_f32_32x32x16_bf16(KA0, qA0, fz, 0, 0, 0); \
    f32x16 stB = __builtin_amdgcn_mfma_f32_32x32x16_bf16(KA0, qB0, fz, 0, 0, 0); \
    stA = __builtin_amdgcn_mfma_f32_32x32x16_bf16(KA1, qA1, stA, 0, 0, 0); \
    stB = __builtin_amdgcn_mfma_f32_32x32x16_bf16(KA1, qB1, stB, 0, 0, 0); \
    stA = __builtin_amdgcn_mfma_f32_32x32x16_bf16(KA2, qA2, stA, 0, 0, 0); \
    stB = __builtin_amdgcn_mfma_f32_32x32x16_bf16(KA2, qB2, stB, 0, 0, 0); \
    stA = __builtin_amdgcn_mfma_f32_32x32x16_bf16(KA3, qA3, stA, 0, 0, 0); \
    stB = __builtin_amdgcn_mfma_f32_32x32x16_bf16(KA3, qB3, stB, 0, 0, 0);

#define PV_CLUSTER(PV0,PV1,PV2,PV3) \
    aAa = __builtin_amdgcn_mfma_f32_32x32x16_bf16(paA0, PV0, aAa, 0, 0, 0); \
    aBa = __builtin_amdgcn_mfma_f32_32x32x16_bf16(paA0, PV1, aBa, 0, 0, 0); \
    aAb = __builtin_amdgcn_mfma_f32_32x32x16_bf16(paB0, PV0, aAb, 0, 0, 0); \
    aBb = __builtin_amdgcn_mfma_f32_32x32x16_bf16(paB0, PV1, aBb, 0, 0, 0); \
    aAa = __builtin_amdgcn_mfma_f32_32x32x16_bf16(paA1, PV2, aAa, 0, 0, 0); \
    aBa = __builtin_amdgcn_mfma_f32_32x32x16_bf16(paA1, PV3, aBa, 0, 0, 0); \
    aAb = __builtin_amdgcn_mfma_f32_32x32x16_bf16(paB1, PV2, aAb, 0, 0, 0); \
    aBb = __builtin_amdgcn_mfma_f32_32x32x16_bf16(paB1, PV3, aBb, 0, 0, 0);

// branch-free mid-iteration (IT=1..30): loads + PV(t-1) + St + softmax
#define ATT_MID(KTP, VTP, KA0,KA1,KA2,KA3, KN0,KN1,KN2,KN3, PV0,PV1,PV2,PV3, PN0,PN1,PN2,PN3) \
  { \
    KN0 = LD8(KTP);        KN1 = LD8(KTP + 1024); \
    KN2 = LD8(KTP + 2048); KN3 = LD8(KTP + 3072); \
    PN0 = LD8(VTP);        PN1 = LD8(VTP + 256); \
    PN2 = LD8(VTP + 1024); PN3 = LD8(VTP + 1280); \
    __builtin_amdgcn_s_setprio(1); \
    PV_CLUSTER(PV0, PV1, PV2, PV3) \
    ST_CLUSTER(KA0, KA1, KA2, KA3) \
    __builtin_amdgcn_s_setprio(0); \
    DO_SOFTMAX_PACK(stA, stB) \
  }

  // ---- peeled IT=0 (even: KA=ka, KN=kn, PN=vn): no PV
  {
    const __bf16* kt_ = kb + 4096 + kof0;    // K tile 1
    const __bf16* vt_ = vb + vof0;           // V tile 0
    kn0 = LD8(kt_);        kn1 = LD8(kt_ + 1024);
    kn2 = LD8(kt_ + 2048); kn3 = LD8(kt_ + 3072);
    vn0 = LD8(vt_);        vn1 = LD8(vt_ + 256);
    vn2 = LD8(vt_ + 1024); vn3 = LD8(vt_ + 1280);
    __builtin_amdgcn_s_setprio(1);
    ST_CLUSTER(ka0, ka1, ka2, ka3)
    __builtin_amdgcn_s_setprio(0);
    DO_SOFTMAX_PACK(stA, stB)
  }

  // ---- branch-free core: IT = 1..30 (15 odd/even pairs), running pointers
  const __bf16* kp = kb + 2 * 4096 + kof0;   // K tile 2 (prefetched at IT=1)
  const __bf16* vp = vb + 4096 + vof0;       // V tile 1 (loaded at IT=1)
  for (int itp = 0; itp < 15; itp++) {
    // odd IT: KA=kn, KN=ka, PV=vn, PN=va
    ATT_MID(kp, vp, kn0,kn1,kn2,kn3, ka0,ka1,ka2,ka3, vn0,vn1,vn2,vn3, va0,va1,va2,va3)
    kp += 4096; vp += 4096;
    // even IT: KA=ka, KN=kn, PV=va, PN=vn
    ATT_MID(kp, vp, ka0,ka1,ka2,ka3, kn0,kn1,kn2,kn3, va0,va1,va2,va3, vn0,vn1,vn2,vn3)
    kp += 4096; vp += 4096;
  }

  // ---- peeled IT=31 (odd: KA=kn, PV=vn(V30), PN=va(V31)): no K prefetch
  {
    va0 = LD8(vp);        va1 = LD8(vp + 256);
    va2 = LD8(vp + 1024); va3 = LD8(vp + 1280);
    __builtin_amdgcn_s_setprio(1);
    PV_CLUSTER(vn0, vn1, vn2, vn3)
    ST_CLUSTER(kn0, kn1, kn2, kn3)
    __builtin_amdgcn_s_setprio(0);
    DO_SOFTMAX_PACK(stA, stB)
  }
#undef ATT_MID
#undef LD8

  // drain: PV of tile 31 (V set va, loaded at IT=31), both streams
  PV_CLUSTER(va0, va1, va2, va3)

  // combine li across the two half-waves (one permlane per stream)
  {
    unsigned int a = __builtin_bit_cast(unsigned int, liA), s = a;
    plswap(a, s);
    liA = __builtin_bit_cast(float, a) + __builtin_bit_cast(float, s);
  }
  {
    unsigned int a = __builtin_bit_cast(unsigned int, liB), s = a;
    plswap(a, s);
    liB = __builtin_bit_cast(float, a) + __builtin_bit_cast(float, s);
  }

  // epilogue: two passes (stream A rows, then stream B rows +64) through fsm.
  float* xbf = fsm;                      // 4 waves x 1024 f32
  float* lb  = fsm + 4096;               // 128 floats
  const int pw = 2 * (1 - wj) + wi;      // partner wave (same wi, other wj)

  // ---- stream A
#pragma unroll
  for (int r = 0; r < 16; r++)
    xbf[w * 1024 + r * 64 + l] = wj ? aAa[r] : aBa[r];
  if (l < 32) lb[w * 32 + l] = liA;
  __syncthreads();
#pragma unroll
  for (int r = 0; r < 16; r++) {
    const int iloc = (r & 3) + 8 * (r >> 2) + 4 * hl;
    const float lt = lb[wi * 32 + iloc] + lb[(wi + 2) * 32 + iloc];
    const float own = wj ? aBa[r] : aAa[r];
    const float o = own + xbf[pw * 1024 + r * 64 + l];
    const long row = q_row0 + wi * 32 + iloc;
    const long col = (long)head * 64 + wj * 32 + (l & 31);
    O[row * 1024 + col] = (__bf16)(o / lt);
  }
  __syncthreads();

  // ---- stream B (rows +64)
#pragma unroll
  for (int r = 0; r < 16; r++)
    xbf[w * 1024 + r * 64 + l] = wj ? aAb[r] : aBb[r];
  if (l < 32) lb[w * 32 + l] = liB;
  __syncthreads();
#pragma unroll
  for (int r = 0; r < 16; r++) {
    const int iloc = (r & 3) + 8 * (r >> 2) + 4 * hl;
    const float lt = lb[wi * 32 + iloc] + lb[(wi + 2) * 32 + iloc];
    const float own = wj ? aBb[r] : aAb[r];
    const float o = own + xbf[pw * 1024 + r * 64 + l];
    const long row = q_row0 + 64 + wi * 32 + iloc;
    const long col = (long)head * 64 + wj * 32 + (l & 31);
    O[row * 1024 + col] = (__bf16)(o / lt);
  }
}

extern "C" void kernel_launch(void* const* d_in, const int* in_sizes, int n_in,
                              void* d_out, int out_size, void* d_ws, size_t ws_size,
                              hipStream_t stream) {
  const void* x    = d_in[0];
  const void* Wqkv = d_in[1];
  const void* Wout = d_in[2];
  const void* bout = d_in[3];

  char* ws = (char*)d_ws;
  int*    flagp = (int*)ws;
  __bf16* xb    = (__bf16*)(ws + 4096);                      // 8 MB (dead after gemm_qkv)
  __bf16* Obuf  = xb;                                        // alias
  __bf16* WqkvT = (__bf16*)(ws + 4096 +  8388608);           // 6 MB
  __bf16* WoutT = (__bf16*)(ws + 4096 + 14680064);           // 2 MB
  __bf16* qbuf  = (__bf16*)(ws + 4096 + 16777216);           // 8 MB  Q [4096][1024]
  __bf16* kbuf  = (__bf16*)(ws + 4096 + 25165824);           // 8 MB  K' frag-native
  __bf16* vbuf  = (__bf16*)(ws + 4096 + 33554432);           // 8 MB  V' frag-native

  hipLaunchKernelGGL(prep, dim3(3072), dim3(256), 0, stream,
                     x, Wqkv, Wout, xb, WqkvT, WoutT, flagp);
  hipLaunchKernelGGL(gemm_qkv, dim3(32, 24), dim3(256), 0, stream,
                     xb, WqkvT, qbuf, kbuf, vbuf);
  hipLaunchKernelGGL(attn_kernel, dim3(32, 16), dim3(256), 0, stream,
                     qbuf, kbuf, vbuf, Obuf);
  hipLaunchKernelGGL(gemm_out, dim3(32, 8), dim3(256), 0, stream,
                     Obuf, WoutT, bout, d_out, flagp);
}

// Round 14
// 181.221 us; speedup vs baseline: 1.0128x; 1.0128x over previous
//
#include <hip/hip_runtime.h>

typedef __bf16 bf16x8 __attribute__((ext_vector_type(8)));
typedef __bf16 bf16x4 __attribute__((ext_vector_type(4)));
typedef __bf16 bf16x2 __attribute__((ext_vector_type(2)));
typedef float f32x4 __attribute__((ext_vector_type(4)));
typedef float f32x16 __attribute__((ext_vector_type(16)));
typedef int i32x4 __attribute__((ext_vector_type(4)));
typedef unsigned int u32x2 __attribute__((ext_vector_type(2)));

#define EXP2_SCALE 0.045084439f   // (1/32) * log2(e), folded into Q at gemm_qkv

__device__ __forceinline__ void async16(void* lds, const void* g) {
  __builtin_amdgcn_global_load_lds(
      (__attribute__((address_space(1))) unsigned int*)(g),
      (__attribute__((address_space(3))) unsigned int*)(lds), 16, 0, 0);
}

__device__ __forceinline__ unsigned int pack2(float a, float b) {
  bf16x2 t;
  t[0] = (__bf16)a;
  t[1] = (__bf16)b;
  return __builtin_bit_cast(unsigned int, t);
}

// raw v_exp_f32 (2^x): skips ocml's denormal-guard expansion.
__device__ __forceinline__ float fexp2(float x) {
#if __has_builtin(__builtin_amdgcn_exp2f)
  return __builtin_amdgcn_exp2f(x);
#else
  return exp2f(x);
#endif
}

// lane[i] <-> lane[i+32] half-wave exchange: d.hi <-> s.lo.
__device__ __forceinline__ void plswap(unsigned int& d, unsigned int& s) {
#if __has_builtin(__builtin_amdgcn_permlane32_swap)
  u32x2 r = __builtin_amdgcn_permlane32_swap(d, s, false, false);
  d = r[0];
  s = r[1];
#else
  asm("v_permlane32_swap_b32 %0, %1" : "+v"(d), "+v"(s));
#endif
}

// Per-block dtype self-detect on a 2048-u16 window.
__device__ __forceinline__ int detect_block(const unsigned short* win, int* cnt_sh) {
  if (threadIdx.x == 0) *cnt_sh = 0;
  __syncthreads();
  int c = 0;
#pragma unroll
  for (int j = 0; j < 8; j++) {
    const unsigned short u = win[threadIdx.x * 8 + j];
    if (((u >> 7) & 0xFF) >= 0xC0) c++;
  }
  if (c) atomicAdd(cnt_sh, c);
  __syncthreads();
  return (*cnt_sh >= 64) ? 1 : 0;
}

// ---------------- prep: x->bf16 cvt (blocks 0..2047) + Wqkv transpose
// (2048..2815) + Wout transpose (2816..3071). W-path global reads vectorized
// (bf16x8 / 2x f32x4) and transposed stores written as bf16x8 (R10-verified).
__global__ __launch_bounds__(256) void prep(
    const void* __restrict__ x, const void* __restrict__ Wqkv,
    const void* __restrict__ Wout, __bf16* __restrict__ xb,
    __bf16* __restrict__ WqkvT, __bf16* __restrict__ WoutT,
    int* __restrict__ flagp)
{
  __shared__ __bf16 tile[64 * 65];
  __shared__ int cnt;
  const int bx = blockIdx.x;
  const int t = threadIdx.x;

  if (bx < 2048) {
    const long base = (long)bx * 2048;
    const int f = detect_block((const unsigned short*)x + base, &cnt);
    if (bx == 0 && t == 0) *flagp = f;
    const long i = base + t * 8;
    if (f) {
      const f32x4* s4 = (const f32x4*)((const float*)x + i);
      const f32x4 v0 = s4[0], v1 = s4[1];
      bf16x8 o;
#pragma unroll
      for (int j = 0; j < 4; j++) o[j] = (__bf16)v0[j];
#pragma unroll
      for (int j = 0; j < 4; j++) o[4 + j] = (__bf16)v1[j];
      *(bf16x8*)&xb[i] = o;
    } else {
      *(bf16x8*)&xb[i] = *(const bf16x8*)((const __bf16*)x + i);
    }
    return;
  }

  const void* in;  __bf16* out;  int R = 1024, C, tcx, tr;
  if (bx < 2816) {
    const int idx = bx - 2048;
    in = Wqkv; out = WqkvT; C = 3072; tcx = (idx % 48) * 64; tr = (idx / 48) * 64;
  } else {
    const int idx = bx - 2816;
    in = Wout; out = WoutT; C = 1024; tcx = (idx % 16) * 64; tr = (idx / 16) * 64;
  }
  const int f = detect_block((const unsigned short*)in + (long)tr * C + tcx, &cnt);
#pragma unroll
  for (int j = 0; j < 2; j++) {
    const int i8 = t * 2 + j;              // 0..511
    const int r = i8 >> 3, c8 = (i8 & 7) * 8;
    const long g = (long)(tr + r) * C + tcx + c8;
    if (f) {
      const f32x4* s4 = (const f32x4*)((const float*)in + g);
      const f32x4 v0 = s4[0], v1 = s4[1];
#pragma unroll
      for (int e = 0; e < 4; e++) tile[r * 65 + c8 + e] = (__bf16)v0[e];
#pragma unroll
      for (int e = 0; e < 4; e++) tile[r * 65 + c8 + 4 + e] = (__bf16)v1[e];
    } else {
      const bf16x8 v = *(const bf16x8*)((const __bf16*)in + g);
#pragma unroll
      for (int e = 0; e < 8; e++) tile[r * 65 + c8 + e] = v[e];
    }
  }
  __syncthreads();
#pragma unroll
  for (int j = 0; j < 2; j++) {
    const int i8 = t * 2 + j;
    const int ro = i8 >> 3, co8 = (i8 & 7) * 8;
    bf16x8 v;
#pragma unroll
    for (int e = 0; e < 8; e++) v[e] = tile[(co8 + e) * 65 + ro];
    *(bf16x8*)&out[(long)(tcx + ro) * R + tr + co8] = v;
  }
}

// ---------------- qkv GEMM: [4096,1024] x [1024,3072]^T, prefetch-pipelined.
// Epilogue writes FRAGMENT-NATIVE global layouts for attn:
//   Q  -> qbuf[row][hd]      (pre-scaled by EXP2_SCALE, stride 1024)
//   K  -> K'[bh][kt][g=d>>3][key&63][e=d&7]   (one b128 per attn A-frag)
//   V  -> V'[bh][kt][g=key>>3&7][d][e=key&7]  (one b128 per attn B-frag)
// K' epilogue LDS-repacked (R9). XCD-bijective swizzle (768 = 8*96).
__global__ __launch_bounds__(256, 3) void gemm_qkv(
    const __bf16* __restrict__ A, const __bf16* __restrict__ Bt,
    __bf16* __restrict__ Qb, __bf16* __restrict__ Kc, __bf16* __restrict__ Vc)
{
  __shared__ __bf16 smem[17408];
  const int t = threadIdx.x;
  const int l = t & 63;
  const int w = t >> 6;
  const int wr = w >> 1, wc = w & 1;
  const int lid = blockIdx.y * 32 + blockIdx.x;
  const int s = (lid & 7) * 96 + (lid >> 3);
  const long m0 = (long)(s & 31) * 128;
  const long n0 = (long)(s >> 5) * 128;
  const int K = 1024;

  const int srow = w * 16 + (l >> 2);
  const int skof = (l & 3) * 8;
  const __bf16* gA = A + (m0 + srow) * (long)K + skof;
  const __bf16* gB = Bt + (n0 + srow) * (long)K + skof;
  const int Ao[2] = {0, 8192}, Bo[2] = {4096, 12288};
  const int lof = w * 512 + l * 8;

  async16(smem + Ao[0] + lof,        gA);
  async16(smem + Ao[0] + 2048 + lof, gA + 64 * (long)K);
  async16(smem + Bo[0] + lof,        gB);
  async16(smem + Bo[0] + 2048 + lof, gB + 64 * (long)K);
  gA += 32; gB += 32;
  __syncthreads();

  f32x4 acc[4][4] = {};

  for (int it = 0; it < 32; it++) {
    if (it < 31) {
      const int nb = (it + 1) & 1;
      async16(smem + Ao[nb] + lof,        gA);
      async16(smem + Ao[nb] + 2048 + lof, gA + 64 * (long)K);
      async16(smem + Bo[nb] + lof,        gB);
      async16(smem + Bo[nb] + 2048 + lof, gB + 64 * (long)K);
      gA += 32; gB += 32;
    }
    const __bf16* As = smem + Ao[it & 1];
    const __bf16* Bs = smem + Bo[it & 1];
    bf16x8 af[4], bfr[4];
#pragma unroll
    for (int mi = 0; mi < 4; mi++)
      af[mi] = *(const bf16x8*)&As[(wr * 64 + mi * 16 + (l & 15)) * 32 + (l >> 4) * 8];
#pragma unroll
    for (int ni = 0; ni < 4; ni++)
      bfr[ni] = *(const bf16x8*)&Bs[(wc * 64 + ni * 16 + (l & 15)) * 32 + (l >> 4) * 8];
#pragma unroll
    for (int mi = 0; mi < 4; mi++)
#pragma unroll
      for (int ni = 0; ni < 4; ni++)
        acc[mi][ni] = __builtin_amdgcn_mfma_f32_16x16x32_bf16(af[mi], bfr[ni], acc[mi][ni], 0, 0, 0);
    __syncthreads();
  }

  if (n0 < 1024) {                       // Q (pre-scaled, stride 1024)
#pragma unroll
    for (int mi = 0; mi < 4; mi++)
#pragma unroll
      for (int ni = 0; ni < 4; ni++) {
        const long col = n0 + wc * 64 + ni * 16 + (l & 15);
#pragma unroll
        for (int r = 0; r < 4; r++) {
          const long row = m0 + wr * 64 + mi * 16 + (l >> 4) * 4 + r;
          Qb[row * 1024 + col] = (__bf16)(acc[mi][ni][r] * EXP2_SCALE);
        }
      }
  } else if (n0 < 2048) {                // K -> fragment-native K' (LDS repack)
#pragma unroll
    for (int mi = 0; mi < 4; mi++)
#pragma unroll
      for (int ni = 0; ni < 4; ni++) {
        const int dcol = wc * 64 + ni * 16 + (l & 15);
        const int kl0 = wr * 64 + mi * 16 + (l >> 4) * 4;
#pragma unroll
        for (int r = 0; r < 4; r++)
          smem[(kl0 + r) * 136 + dcol] = (__bf16)acc[mi][ni][r];
      }
    __syncthreads();
    const int b = (int)(m0 >> 11);
    const int nbase = (int)(m0 & 2047);
#pragma unroll
    for (int i = 0; i < 8; i++) {
      const int kl = (t >> 4) + i * 16;          // key_local 0..127
      const int d0 = (t & 15) * 8;               // feature col base 0..120
      const bf16x8 v = *(const bf16x8*)&smem[kl * 136 + d0];
      const int col1 = (int)(n0 - 1024) + d0;    // h*64 + d (d0 multiple of 8)
      const int h = col1 >> 6, d = col1 & 63;
      const int n = nbase + kl;                  // key
      const long addr = ((long)(b * 16 + h) * 32 + (n >> 6)) * 4096 + (d >> 3) * 512 + (n & 63) * 8;
      *(bf16x8*)&Kc[addr] = v;
    }
  } else {                               // V -> fragment-native V'
#pragma unroll
    for (int mi = 0; mi < 4; mi++)
#pragma unroll
      for (int ni = 0; ni < 4; ni++) {
        const int c = wc * 64 + ni * 16 + (l & 15);
        const int r = wr * 64 + mi * 16 + (l >> 4) * 4;
        bf16x4 pk;
#pragma unroll
        for (int k = 0; k < 4; k++) pk[k] = (__bf16)acc[mi][ni][k];
        *(bf16x4*)&smem[c * 136 + r] = pk;
      }
    __syncthreads();
    const int b = (int)(m0 >> 11);
    const int nbase = (int)(m0 & 2047);
#pragma unroll
    for (int i = 0; i < 8; i++) {
      const int c = (t >> 4) + i * 16;
      const int r8 = (t & 15) * 8;
      const bf16x8 v = *(const bf16x8*)&smem[c * 136 + r8];
      const int vcol = (int)(n0 - 2048) + c;         // h*64 + d
      const int h = vcol >> 6, d = vcol & 63;
      const int n = nbase + r8;                      // key base of the 8
      const long addr = ((long)(b * 16 + h) * 32 + (n >> 6)) * 4096 + ((n >> 3) & 7) * 512 + d * 8;
      *(bf16x8*)&Vc[addr] = v;
    }
  }
}

// ---------------- out GEMM: [4096,1024] x [1024,1024]^T + bias, 128x128 tile
// (gemm_qkv's verified main loop). Grid 32x8, XCD-bijective swizzle.
__global__ __launch_bounds__(256, 3) void gemm_out(
    const __bf16* __restrict__ A, const __bf16* __restrict__ Bt,
    const void* __restrict__ bias_raw, void* __restrict__ C,
    const int* __restrict__ flagp)
{
  __shared__ __bf16 smem[16384];
  const int t = threadIdx.x;
  const int l = t & 63;
  const int w = t >> 6;
  const int wr = w >> 1, wc = w & 1;
  const int lid = blockIdx.y * 32 + blockIdx.x;
  const int s = (lid & 7) * 32 + (lid >> 3);
  const long m0 = (long)(s & 31) * 128;
  const long n0 = (long)(s >> 5) * 128;
  const int of = *flagp;
  const int K = 1024;

  const int srow = w * 16 + (l >> 2);
  const int skof = (l & 3) * 8;
  const __bf16* gA = A + (m0 + srow) * (long)K + skof;
  const __bf16* gB = Bt + (n0 + srow) * (long)K + skof;
  const int Ao[2] = {0, 8192}, Bo[2] = {4096, 12288};
  const int lof = w * 512 + l * 8;

  async16(smem + Ao[0] + lof,        gA);
  async16(smem + Ao[0] + 2048 + lof, gA + 64 * (long)K);
  async16(smem + Bo[0] + lof,        gB);
  async16(smem + Bo[0] + 2048 + lof, gB + 64 * (long)K);
  gA += 32; gB += 32;
  __syncthreads();

  f32x4 acc[4][4] = {};

  for (int it = 0; it < 32; it++) {
    if (it < 31) {
      const int nb = (it + 1) & 1;
      async16(smem + Ao[nb] + lof,        gA);
      async16(smem + Ao[nb] + 2048 + lof, gA + 64 * (long)K);
      async16(smem + Bo[nb] + lof,        gB);
      async16(smem + Bo[nb] + 2048 + lof, gB + 64 * (long)K);
      gA += 32; gB += 32;
    }
    const __bf16* As = smem + Ao[it & 1];
    const __bf16* Bs = smem + Bo[it & 1];
    bf16x8 af[4], bfr[4];
#pragma unroll
    for (int mi = 0; mi < 4; mi++)
      af[mi] = *(const bf16x8*)&As[(wr * 64 + mi * 16 + (l & 15)) * 32 + (l >> 4) * 8];
#pragma unroll
    for (int ni = 0; ni < 4; ni++)
      bfr[ni] = *(const bf16x8*)&Bs[(wc * 64 + ni * 16 + (l & 15)) * 32 + (l >> 4) * 8];
#pragma unroll
    for (int mi = 0; mi < 4; mi++)
#pragma unroll
      for (int ni = 0; ni < 4; ni++)
        acc[mi][ni] = __builtin_amdgcn_mfma_f32_16x16x32_bf16(af[mi], bfr[ni], acc[mi][ni], 0, 0, 0);
    __syncthreads();
  }

#pragma unroll
  for (int mi = 0; mi < 4; mi++)
#pragma unroll
    for (int ni = 0; ni < 4; ni++) {
      const long col = n0 + wc * 64 + ni * 16 + (l & 15);
      const float bv = of ? ((const float*)bias_raw)[col]
                          : (float)((const __bf16*)bias_raw)[col];
#pragma unroll
      for (int r = 0; r < 4; r++) {
        const long row = m0 + wr * 64 + mi * 16 + (l >> 4) * 4 + r;
        const float val = acc[mi][ni][r] + bv;
        const long off = row * 1024 + col;
        if (of) ((float*)C)[off] = val;
        else    ((__bf16*)C)[off] = (__bf16)val;
      }
    }
}

// ---------------- flash attention, ZERO-LDS / ZERO-BARRIER, DUAL-Q-STREAM.
// R14 = R11 exactly (session-best: attn 43.6-43.8us). PV-first MFMA cluster
// (the ready register-only PV hides the K-load vmcnt wait at iteration
// entry); VALU row-sum overlapped under MFMA; runtime IT guards kept (the
// compiler's schedule for this exact source is a measured local optimum —
// lsum-MFMA, St-first, and loop-peel variants all regressed).
__global__ __launch_bounds__(256, 2) void attn_kernel(
    const __bf16* __restrict__ Qb, const __bf16* __restrict__ Kc,
    const __bf16* __restrict__ Vc, __bf16* __restrict__ O)
{
  __shared__ float fsm[4 * 1024 + 128];
  const int t = threadIdx.x;
  const int l = t & 63;
  const int w = t >> 6;
  const int wi = w & 1, wj = w >> 1;
  const int hl = l >> 5;
  // XCD swizzle: same bh => same (linear % 8) => same XCD L2.
  const int L = blockIdx.y * 32 + blockIdx.x;
  const int bh = (L & 7) * 4 + ((L >> 3) & 3);
  const int qt = L >> 5;                 // 0..15 (128-row Q tiles)
  const int b = bh >> 4, head = bh & 15;
  const long q_row0 = (long)b * 2048 + qt * 128;

  // Q fragments for both streams (pre-scaled upstream)
  bf16x8 qA0, qA1, qA2, qA3, qB0, qB1, qB2, qB3;
  {
    const __bf16* gQ = Qb + (q_row0 + wi * 32 + (l & 31)) * 1024 + head * 64 + hl * 8;
    qA0 = *(const bf16x8*)(gQ);
    qA1 = *(const bf16x8*)(gQ + 16);
    qA2 = *(const bf16x8*)(gQ + 32);
    qA3 = *(const bf16x8*)(gQ + 48);
    gQ += (long)64 * 1024;
    qB0 = *(const bf16x8*)(gQ);
    qB1 = *(const bf16x8*)(gQ + 16);
    qB2 = *(const bf16x8*)(gQ + 32);
    qB3 = *(const bf16x8*)(gQ + 48);
  }

  const __bf16* kb = Kc + (long)bh * 131072;
  const __bf16* vb = Vc + (long)bh * 131072;
  // K A-frag: (g = kc*2+hl, key = wj*32+(l&31)); frag kc offset = kof0 + kc*1024
  const int kof0 = hl * 512 + (wj * 32 + (l & 31)) * 8;
  // V B-frag: (g = wj*4 + {hl, 2+hl}, d = {l&31, 32+(l&31)})
  const int vof0 = (wj * 4 + hl) * 512 + (l & 31) * 8;   // +256 dhi, +1024 g+2

  f32x16 aAa = {0,0,0,0,0,0,0,0,0,0,0,0,0,0,0,0};  // stream A, d 0..31
  f32x16 aBa = {0,0,0,0,0,0,0,0,0,0,0,0,0,0,0,0};  // stream A, d 32..63
  f32x16 aAb = {0,0,0,0,0,0,0,0,0,0,0,0,0,0,0,0};  // stream B, d 0..31
  f32x16 aBb = {0,0,0,0,0,0,0,0,0,0,0,0,0,0,0,0};  // stream B, d 32..63
  const f32x16 fz = {0,0,0,0,0,0,0,0,0,0,0,0,0,0,0,0};
  float liA = 0.0f, liB = 0.0f;
  bf16x8 paA0 = {}, paA1 = {}, paB0 = {}, paB1 = {};

#define LD8(p) (*(const bf16x8*)(p))
  // tile-0 K into set a
  bf16x8 ka0 = LD8(kb + kof0),        ka1 = LD8(kb + kof0 + 1024);
  bf16x8 ka2 = LD8(kb + kof0 + 2048), ka3 = LD8(kb + kof0 + 3072);
  bf16x8 kn0, kn1, kn2, kn3;
  bf16x8 va0 = {}, va1 = {}, va2 = {}, va3 = {};
  bf16x8 vn0, vn1, vn2, vn3;

#define SM_PACK(ST, PA0, PA1) \
  { \
    unsigned int a0 = pack2(ST[0],  ST[1]),  b0 = pack2(ST[4],  ST[5]); \
    unsigned int c0 = pack2(ST[2],  ST[3]),  d0 = pack2(ST[6],  ST[7]); \
    unsigned int a1 = pack2(ST[8],  ST[9]),  b1 = pack2(ST[12], ST[13]); \
    unsigned int c1 = pack2(ST[10], ST[11]), d1 = pack2(ST[14], ST[15]); \
    plswap(a0, b0); plswap(c0, d0); plswap(a1, b1); plswap(c1, d1); \
    const i32x4 f0_ = {(int)a0, (int)c0, (int)b0, (int)d0}; \
    const i32x4 f1_ = {(int)a1, (int)c1, (int)b1, (int)d1}; \
    PA0 = __builtin_bit_cast(bf16x8, f0_); \
    PA1 = __builtin_bit_cast(bf16x8, f1_); \
  }

#define ATT_ITER(IT, KA0,KA1,KA2,KA3, KN0,KN1,KN2,KN3, PV0,PV1,PV2,PV3, PN0,PN1,PN2,PN3) \
  { \
    const __bf16* kt_ = kb + (IT + 1) * 4096 + kof0; \
    const __bf16* vt_ = vb + (IT) * 4096 + vof0; \
    if ((IT) < 31) { \
      KN0 = LD8(kt_); KN1 = LD8(kt_ + 1024); \
      KN2 = LD8(kt_ + 2048); KN3 = LD8(kt_ + 3072); \
    } \
    PN0 = LD8(vt_);        PN1 = LD8(vt_ + 256); \
    PN2 = LD8(vt_ + 1024); PN3 = LD8(vt_ + 1280); \
    __builtin_amdgcn_s_setprio(1); \
    if ((IT) > 0) { \
      aAa = __builtin_amdgcn_mfma_f32_32x32x16_bf16(paA0, PV0, aAa, 0, 0, 0); \
      aBa = __builtin_amdgcn_mfma_f32_32x32x16_bf16(paA0, PV1, aBa, 0, 0, 0); \
      aAb = __builtin_amdgcn_mfma_f32_32x32x16_bf16(paB0, PV0, aAb, 0, 0, 0); \
      aBb = __builtin_amdgcn_mfma_f32_32x32x16_bf16(paB0, PV1, aBb, 0, 0, 0); \
      aAa = __builtin_amdgcn_mfma_f32_32x32x16_bf16(paA1, PV2, aAa, 0, 0, 0); \
      aBa = __builtin_amdgcn_mfma_f32_32x32x16_bf16(paA1, PV3, aBa, 0, 0, 0); \
      aAb = __builtin_amdgcn_mfma_f32_32x32x16_bf16(paB1, PV2, aAb, 0, 0, 0); \
      aBb = __builtin_amdgcn_mfma_f32_32x32x16_bf16(paB1, PV3, aBb, 0, 0, 0); \
    } \
    f32x16 stA = __builtin_amdgcn_mfma_f32_32x32x16_bf16(KA0, qA0, fz, 0, 0, 0); \
    f32x16 stB = __builtin_amdgcn_mfma_f32_32x32x16_bf16(KA0, qB0, fz, 0, 0, 0); \
    stA = __builtin_amdgcn_mfma_f32_32x32x16_bf16(KA1, qA1, stA, 0, 0, 0); \
    stB = __builtin_amdgcn_mfma_f32_32x32x16_bf16(KA1, qB1, stB, 0, 0, 0); \
    stA = __builtin_amdgcn_mfma_f32_32x32x16_bf16(KA2, qA2, stA, 0, 0, 0); \
    stB = __builtin_amdgcn_mfma_f32_32x32x16_bf16(KA2, qB2, stB, 0, 0, 0); \
    stA = __builtin_amdgcn_mfma_f32_32x32x16_bf16(KA3, qA3, stA, 0, 0, 0); \
    stB = __builtin_amdgcn_mfma_f32_32x32x16_bf16(KA3, qB3, stB, 0, 0, 0); \
    __builtin_amdgcn_s_setprio(0); \
    float rsA0 = 0.0f, rsA1 = 0.0f; \
    _Pragma("unroll") \
    for (int r = 0; r < 16; r += 2) { \
      const float p0 = fexp2(stA[r]); \
      const float p1 = fexp2(stA[r + 1]); \
      stA[r] = p0; stA[r + 1] = p1; \
      rsA0 += p0; rsA1 += p1; \
    } \
    liA += rsA0 + rsA1; \
    SM_PACK(stA, paA0, paA1) \
    float rsB0 = 0.0f, rsB1 = 0.0f; \
    _Pragma("unroll") \
    for (int r = 0; r < 16; r += 2) { \
      const float p0 = fexp2(stB[r]); \
      const float p1 = fexp2(stB[r + 1]); \
      stB[r] = p0; stB[r + 1] = p1; \
      rsB0 += p0; rsB1 += p1; \
    } \
    liB += rsB0 + rsB1; \
    SM_PACK(stB, paB0, paB1) \
  }

  for (int itp = 0; itp < 16; itp++) {
    const int it0 = itp * 2, it1 = itp * 2 + 1;
    ATT_ITER(it0, ka0,ka1,ka2,ka3, kn0,kn1,kn2,kn3, va0,va1,va2,va3, vn0,vn1,vn2,vn3)
    ATT_ITER(it1, kn0,kn1,kn2,kn3, ka0,ka1,ka2,ka3, vn0,vn1,vn2,vn3, va0,va1,va2,va3)
  }
#undef ATT_ITER
#undef LD8

  // drain: PV of tile 31 (V set va, loaded at it=31), both streams
  aAa = __builtin_amdgcn_mfma_f32_32x32x16_bf16(paA0, va0, aAa, 0, 0, 0);
  aBa = __builtin_amdgcn_mfma_f32_32x32x16_bf16(paA0, va1, aBa, 0, 0, 0);
  aAb = __builtin_amdgcn_mfma_f32_32x32x16_bf16(paB0, va0, aAb, 0, 0, 0);
  aBb = __builtin_amdgcn_mfma_f32_32x32x16_bf16(paB0, va1, aBb, 0, 0, 0);
  aAa = __builtin_amdgcn_mfma_f32_32x32x16_bf16(paA1, va2, aAa, 0, 0, 0);
  aBa = __builtin_amdgcn_mfma_f32_32x32x16_bf16(paA1, va3, aBa, 0, 0, 0);
  aAb = __builtin_amdgcn_mfma_f32_32x32x16_bf16(paB1, va2, aAb, 0, 0, 0);
  aBb = __builtin_amdgcn_mfma_f32_32x32x16_bf16(paB1, va3, aBb, 0, 0, 0);

  // combine li across the two half-waves (one permlane per stream)
  {
    unsigned int a = __builtin_bit_cast(unsigned int, liA), s = a;
    plswap(a, s);
    liA = __builtin_bit_cast(float, a) + __builtin_bit_cast(float, s);
  }
  {
    unsigned int a = __builtin_bit_cast(unsigned int, liB), s = a;
    plswap(a, s);
    liB = __builtin_bit_cast(float, a) + __builtin_bit_cast(float, s);
  }

  // epilogue: two passes (stream A rows, then stream B rows +64) through fsm.
  float* xbf = fsm;                      // 4 waves x 1024 f32
  float* lb  = fsm + 4096;               // 128 floats
  const int pw = 2 * (1 - wj) + wi;      // partner wave (same wi, other wj)

  // ---- stream A
#pragma unroll
  for (int r = 0; r < 16; r++)
    xbf[w * 1024 + r * 64 + l] = wj ? aAa[r] : aBa[r];
  if (l < 32) lb[w * 32 + l] = liA;
  __syncthreads();
#pragma unroll
  for (int r = 0; r < 16; r++) {
    const int iloc = (r & 3) + 8 * (r >> 2) + 4 * hl;
    const float lt = lb[wi * 32 + iloc] + lb[(wi + 2) * 32 + iloc];
    const float own = wj ? aBa[r] : aAa[r];
    const float o = own + xbf[pw * 1024 + r * 64 + l];
    const long row = q_row0 + wi * 32 + iloc;
    const long col = (long)head * 64 + wj * 32 + (l & 31);
    O[row * 1024 + col] = (__bf16)(o / lt);
  }
  __syncthreads();

  // ---- stream B (rows +64)
#pragma unroll
  for (int r = 0; r < 16; r++)
    xbf[w * 1024 + r * 64 + l] = wj ? aAb[r] : aBb[r];
  if (l < 32) lb[w * 32 + l] = liB;
  __syncthreads();
#pragma unroll
  for (int r = 0; r < 16; r++) {
    const int iloc = (r & 3) + 8 * (r >> 2) + 4 * hl;
    const float lt = lb[wi * 32 + iloc] + lb[(wi + 2) * 32 + iloc];
    const float own = wj ? aBb[r] : aAb[r];
    const float o = own + xbf[pw * 1024 + r * 64 + l];
    const long row = q_row0 + 64 + wi * 32 + iloc;
    const long col = (long)head * 64 + wj * 32 + (l & 31);
    O[row * 1024 + col] = (__bf16)(o / lt);
  }
}

extern "C" void kernel_launch(void* const* d_in, const int* in_sizes, int n_in,
                              void* d_out, int out_size, void* d_ws, size_t ws_size,
                              hipStream_t stream) {
  const void* x    = d_in[0];
  const void* Wqkv = d_in[1];
  const void* Wout = d_in[2];
  const void* bout = d_in[3];

  char* ws = (char*)d_ws;
  int*    flagp = (int*)ws;
  __bf16* xb    = (__bf16*)(ws + 4096);                      // 8 MB (dead after gemm_qkv)
  __bf16* Obuf  = xb;                                        // alias
  __bf16* WqkvT = (__bf16*)(ws + 4096 +  8388608);           // 6 MB
  __bf16* WoutT = (__bf16*)(ws + 4096 + 14680064);           // 2 MB
  __bf16* qbuf  = (__bf16*)(ws + 4096 + 16777216);           // 8 MB  Q [4096][1024]
  __bf16* kbuf  = (__bf16*)(ws + 4096 + 25165824);           // 8 MB  K' frag-native
  __bf16* vbuf  = (__bf16*)(ws + 4096 + 33554432);           // 8 MB  V' frag-native

  hipLaunchKernelGGL(prep, dim3(3072), dim3(256), 0, stream,
                     x, Wqkv, Wout, xb, WqkvT, WoutT, flagp);
  hipLaunchKernelGGL(gemm_qkv, dim3(32, 24), dim3(256), 0, stream,
                     xb, WqkvT, qbuf, kbuf, vbuf);
  hipLaunchKernelGGL(attn_kernel, dim3(32, 16), dim3(256), 0, stream,
                     qbuf, kbuf, vbuf, Obuf);
  hipLaunchKernelGGL(gemm_out, dim3(32, 8), dim3(256), 0, stream,
                     Obuf, WoutT, bout, d_out, flagp);
}